// Round 2
// baseline (589.870 us; speedup 1.0000x reference)
//
#include <hip/hip_runtime.h>

#define D 128
#define SCAN_ELEMS 4096   // elements per scan block (256 threads x 16)

typedef __attribute__((ext_vector_type(8))) short short8;
typedef __attribute__((ext_vector_type(4))) float f32x4;

// ---------------- split-bf16 / fp24 helpers ----------------
__device__ inline void f2bf(float f, short& hi, short& lo) {
    union { float f; unsigned u; } a; a.f = f;
    unsigned r = a.u + 0x7fffu + ((a.u >> 16) & 1u);       // RNE to bf16
    hi = (short)(r >> 16);
    union { unsigned u; float f; } h; h.u = ((unsigned)(unsigned short)hi) << 16;
    union { float f; unsigned u; } b; b.f = f - h.f;
    unsigned r2 = b.u + 0x7fffu + ((b.u >> 16) & 1u);
    lo = (short)(r2 >> 16);
}

// fp24 encode: RNE-round fp32 to 24 bits (sign+8exp+15mant)
__device__ inline unsigned enc24(float f) {
    union { float f; unsigned u; } a; a.f = f;
    unsigned r = a.u + 0x7fu + ((a.u >> 8) & 1u);
    return r >> 8;
}

// Packed chunk-major fp24 layout:
//   xp[chunk][row] = 64B line: bytes [0,32) = 16x hi16, [32,48) = 16x lo8, [48,64) pad.
// One edge-gather per chunk touches exactly ONE 64B cache line.
// decode 4 fp24 elems (cols cg*4..cg*4+3 of the chunk) via v_perm_b32.
__device__ inline void g24p(const unsigned char* __restrict__ cb, int row, int cg, float4& a) {
    const unsigned char* p = cb + ((size_t)row << 6);
    uint2 h2 = *reinterpret_cast<const uint2*>(p + cg * 8);
    unsigned lb = *reinterpret_cast<const unsigned*>(p + 32 + cg * 4);
    union { unsigned u; float f; } v0, v1, v2, v3;
    v0.u = __builtin_amdgcn_perm(h2.x, lb, 0x0504000Cu);  // {h.b1,h.b0,l.b0,0}
    v1.u = __builtin_amdgcn_perm(h2.x, lb, 0x0706010Cu);  // {h.b3,h.b2,l.b1,0}
    v2.u = __builtin_amdgcn_perm(h2.y, lb, 0x0504020Cu);  // {h.b1,h.b0,l.b2,0}
    v3.u = __builtin_amdgcn_perm(h2.y, lb, 0x0706030Cu);  // {h.b3,h.b2,l.b3,0}
    a.x += v0.f; a.y += v1.f; a.z += v2.f; a.w += v3.f;
}

// ---------------- precompute: count (+fused wsplit) ----------------
// deg[] counts REAL edges only (self-loop handled as +1 at use sites).

__device__ void wsplit_body(int tid, const float* __restrict__ W1,
                            const float* __restrict__ W2, const float* __restrict__ W3,
                            short* __restrict__ Bsw) {
    int layer = tid >> 14;
    int rem = tid & 16383;
    int k = rem >> 7, c = rem & 127;
    const float* Wg = (layer == 0) ? W1 : ((layer == 1) ? W2 : W3);
    float v = Wg[k * 128 + c];
    short hi, lo; f2bf(v, hi, lo);
    int ktile = k >> 5, kk = k & 31, q = kk >> 3, j = kk & 7;
    int ct = c >> 4, mm = c & 15, lane = q * 16 + mm;
    int idx = layer * 32768 + ((ktile * 8 + ct) * 64 + lane) * 8 + j;
    Bsw[idx] = hi;
    Bsw[idx + 16384] = lo;
}

__global__ __launch_bounds__(256) void count_wsplit_kernel(const int* __restrict__ dst,
                                                           int* __restrict__ deg,
                                                           unsigned short* __restrict__ rank,
                                                           int e, int nbCount,
                                                           const float* __restrict__ W1,
                                                           const float* __restrict__ W2,
                                                           const float* __restrict__ W3,
                                                           short* __restrict__ Bsw) {
    if ((int)blockIdx.x < nbCount) {
        int i = blockIdx.x * 256 + threadIdx.x;
        if (i < e) rank[i] = (unsigned short)atomicAdd(&deg[dst[i]], 1);
    } else {
        int tid = (blockIdx.x - nbCount) * 256 + threadIdx.x;
        wsplit_body(tid, W1, W2, W3, Bsw);
    }
}

// ---- hierarchical scan ----
__global__ __launch_bounds__(256) void scanA_kernel(const int* __restrict__ deg,
                                                    int* __restrict__ blkSums, int n) {
    __shared__ int waveSums[4];
    int t = threadIdx.x;
    int base = blockIdx.x * SCAN_ELEMS + t * 16;
    int s = 0;
    if (base + 16 <= n) {
        const int4* p = reinterpret_cast<const int4*>(deg + base);
        #pragma unroll
        for (int k = 0; k < 4; ++k) {
            int4 v = p[k];
            s += v.x + v.y + v.z + v.w;
        }
    } else {
        for (int k = 0; k < 16; ++k) {
            int i = base + k;
            if (i < n) s += deg[i];
        }
    }
    #pragma unroll
    for (int off = 32; off > 0; off >>= 1) s += __shfl_down(s, off);
    int lane = t & 63, w = t >> 6;
    if (lane == 0) waveSums[w] = s;
    __syncthreads();
    if (t == 0) blkSums[blockIdx.x] = waveSums[0] + waveSums[1] + waveSums[2] + waveSums[3];
}

__global__ __launch_bounds__(256) void scanC_kernel(const int* __restrict__ deg,
                                                    const int* __restrict__ blkSums,
                                                    int* __restrict__ offsets,
                                                    float* __restrict__ dinv, int n, int nblk,
                                                    float* __restrict__ fcout,
                                                    const float* __restrict__ fcb) {
    __shared__ int waveSums[4];
    __shared__ int blkBase;
    int t = threadIdx.x;
    int lane = t & 63, w = t >> 6;

    if (t < 64) {
        int s = (t < nblk && t < (int)blockIdx.x) ? blkSums[t] : 0;
        #pragma unroll
        for (int off = 32; off > 0; off >>= 1) s += __shfl_down(s, off);
        if (t == 0) blkBase = s;
    }

    int base = blockIdx.x * SCAN_ELEMS + t * 16;
    int v[16];
    int s = 0;
    #pragma unroll
    for (int k = 0; k < 16; ++k) {
        int i = base + k;
        int d = (i < n) ? deg[i] : 0;
        v[k] = d;
        s += d;
    }
    int incl = s;
    #pragma unroll
    for (int off = 1; off < 64; off <<= 1) {
        int u = __shfl_up(incl, off);
        if (lane >= off) incl += u;
    }
    if (lane == 63) waveSums[w] = incl;
    __syncthreads();
    int waveOff = 0;
    for (int i = 0; i < 4; ++i) if (i < w) waveOff += waveSums[i];
    int off0 = blkBase + waveOff + incl - s;

    float b0 = fcb[0];
    #pragma unroll
    for (int k = 0; k < 16; ++k) {
        int i = base + k;
        if (i < n) {
            offsets[i] = off0;
            dinv[i] = rsqrtf((float)(v[k] + 1));   // +1 self-loop
            fcout[i] = b0;                          // init for fused-fc atomics
            off0 += v[k];
        }
    }
}

// ---------------- split-bf16 MFMA GEMM body (no LDS, packed chunk-major fp24 out) ----------------
__device__ void gemm_body(int blk, const float* __restrict__ A,
                          const short* __restrict__ Bsw,
                          const float* __restrict__ dinv,
                          unsigned char* __restrict__ xp, int n, int t) {
    int w = t >> 6;
    int lane = t & 63;
    int quad = lane >> 4;
    int m = lane & 15;

    int rowBase = blk * 64 + w * 16;
    int arow = rowBase + m;
    bool valid = arow < n;
    const float* ap = A + (size_t)(valid ? arow : 0) * D + quad * 8;

    f32x4 acc[8];
    #pragma unroll
    for (int ct = 0; ct < 8; ++ct) acc[ct] = (f32x4){0.f, 0.f, 0.f, 0.f};

    #pragma unroll
    for (int kt = 0; kt < 4; ++kt) {
        short8 a_hi, a_lo;
        {
            float4 f0 = *reinterpret_cast<const float4*>(ap + kt * 32);
            float4 f1 = *reinterpret_cast<const float4*>(ap + kt * 32 + 4);
            float fv[8] = {f0.x, f0.y, f0.z, f0.w, f1.x, f1.y, f1.z, f1.w};
            #pragma unroll
            for (int j = 0; j < 8; ++j) {
                short h, l; f2bf(valid ? fv[j] : 0.f, h, l);
                a_hi[j] = h; a_lo[j] = l;
            }
        }
        const short* bp = Bsw + (kt * 512 + lane) * 8;
        #pragma unroll
        for (int ct = 0; ct < 8; ++ct) {
            short8 b_hi = *reinterpret_cast<const short8*>(bp + ct * 512);
            short8 b_lo = *reinterpret_cast<const short8*>(bp + 16384 + ct * 512);
            acc[ct] = __builtin_amdgcn_mfma_f32_16x16x32_bf16(a_hi, b_hi, acc[ct], 0, 0, 0);
            acc[ct] = __builtin_amdgcn_mfma_f32_16x16x32_bf16(a_hi, b_lo, acc[ct], 0, 0, 0);
            acc[ct] = __builtin_amdgcn_mfma_f32_16x16x32_bf16(a_lo, b_hi, acc[ct], 0, 0, 0);
        }
    }

    // epilogue: C/D layout col=lane&15, row=quad*4+reg; chunk-major packed store
    #pragma unroll
    for (int r = 0; r < 4; ++r) {
        int row = rowBase + quad * 4 + r;
        if (row < n) {
            float s = dinv[row];
            #pragma unroll
            for (int ct = 0; ct < 8; ++ct) {
                unsigned e24 = enc24(acc[ct][r] * s);
                unsigned char* p = xp + (((size_t)ct * n + row) << 6);
                *reinterpret_cast<unsigned short*>(p + 2 * m) = (unsigned short)(e24 >> 8);
                p[32 + m] = (unsigned char)(e24 & 0xffu);
            }
        }
    }
}

__global__ __launch_bounds__(256) void gemm_kernel(const float* __restrict__ A,
                                                   const short* __restrict__ Bsw,
                                                   const float* __restrict__ dinv,
                                                   unsigned char* __restrict__ xp, int n) {
    gemm_body(blockIdx.x, A, Bsw, dinv, xp, n, threadIdx.x);
}

// fill fused with layer-1 gemm (independent work, one dispatch)
__global__ __launch_bounds__(256) void fill_gemm_kernel(const int* __restrict__ src,
                                                        const int* __restrict__ dst,
                                                        const int* __restrict__ offsets,
                                                        const unsigned short* __restrict__ rank,
                                                        unsigned short* __restrict__ csr_src,
                                                        int e, int nbFill,
                                                        const float* __restrict__ A,
                                                        const short* __restrict__ Bsw,
                                                        const float* __restrict__ dinv,
                                                        unsigned char* __restrict__ xp, int n) {
    if ((int)blockIdx.x < nbFill) {
        int i = blockIdx.x * 256 + threadIdx.x;
        if (i < e) csr_src[offsets[dst[i]] + rank[i]] = (unsigned short)src[i];
    } else {
        gemm_body(blockIdx.x - nbFill, A, Bsw, dinv, xp, n, threadIdx.x);
    }
}

// ---------------- chunked XCD-local aggregation ----------------
// chunk = blockIdx.x & 7  -> with round-robin block->XCD dispatch, each XCD's L2
// only caches its own 3.2MB chunk of the feature array -> local-L2 gathers.
// Wave layout: eslot = lane>>2 (16 edges in flight), cg = lane&3 (4 cols each).
// FC=true: layer-3 head fused -- per-node partial dot, atomicAdd into fcout.
template<bool FC>
__global__ __launch_bounds__(256) void aggc_kernel(const unsigned char* __restrict__ xp,
                                                   const unsigned short* __restrict__ csr,
                                                   const int* __restrict__ offsets,
                                                   const int* __restrict__ deg,
                                                   const float* __restrict__ dinv,
                                                   const float* __restrict__ bias,
                                                   float* __restrict__ outp,
                                                   const float* __restrict__ fcw,
                                                   float* __restrict__ fcout,
                                                   int n) {
    int chunk = blockIdx.x & 7;
    int grp = blockIdx.x >> 3;
    int t = threadIdx.x;
    int wv = t >> 6, lane = t & 63;
    int eslot = lane >> 2, cg = lane & 3;

    const unsigned char* cb = xp + ((size_t)chunk * n << 6);
    float4 bv = *reinterpret_cast<const float4*>(bias + chunk * 16 + cg * 4);
    float4 wvv;
    if (FC) wvv = *reinterpret_cast<const float4*>(fcw + chunk * 16 + cg * 4);

    int node0 = grp * 32 + wv * 8;
    for (int i = 0; i < 8; ++i) {
        int node = node0 + i;
        if (node >= n) break;
        int base = offsets[node];
        int cnt  = deg[node];

        float4 acc = make_float4(0.f, 0.f, 0.f, 0.f);
        for (int j = 0; j < cnt; j += 16) {
            int ee = j + eslot;
            if (ee < cnt) g24p(cb, (int)csr[base + ee], cg, acc);
        }
        if (eslot == 0) g24p(cb, node, cg, acc);   // self-loop term

        #pragma unroll
        for (int off = 4; off < 64; off <<= 1) {
            acc.x += __shfl_xor(acc.x, off);
            acc.y += __shfl_xor(acc.y, off);
            acc.z += __shfl_xor(acc.z, off);
            acc.w += __shfl_xor(acc.w, off);
        }

        float di = dinv[node];
        float4 r;
        r.x = fmaxf(di * acc.x + bv.x, 0.f);
        r.y = fmaxf(di * acc.y + bv.y, 0.f);
        r.z = fmaxf(di * acc.z + bv.z, 0.f);
        r.w = fmaxf(di * acc.w + bv.w, 0.f);

        if (FC) {
            float p = r.x * wvv.x + r.y * wvv.y + r.z * wvv.z + r.w * wvv.w;
            p += __shfl_xor(p, 1);
            p += __shfl_xor(p, 2);
            if (lane == 0) atomicAdd(fcout + node, p);
        } else {
            if (eslot == 0)
                *reinterpret_cast<float4*>(outp + (size_t)node * D + chunk * 16 + cg * 4) = r;
        }
    }
}

// ---------------- launch ----------------

extern "C" void kernel_launch(void* const* d_in, const int* in_sizes, int n_in,
                              void* d_out, int out_size, void* d_ws, size_t ws_size,
                              hipStream_t stream) {
    const float* x   = (const float*)d_in[0];
    const int*   ei  = (const int*)d_in[1];
    const float* W1  = (const float*)d_in[2];
    const float* b1  = (const float*)d_in[3];
    const float* W2  = (const float*)d_in[4];
    const float* b2  = (const float*)d_in[5];
    const float* W3  = (const float*)d_in[6];
    const float* b3  = (const float*)d_in[7];
    const float* Wfc = (const float*)d_in[8];
    const float* bfc = (const float*)d_in[9];
    float* outp = (float*)d_out;

    const int n = in_sizes[0] / D;        // 50000
    const int e = in_sizes[1] / 2;        // 800000
    const int* src = ei;
    const int* dst = ei + e;

    char* ws = (char*)d_ws;
    size_t off = 0;
    auto alloc = [&](size_t bytes) {
        void* p = ws + off;
        off += (bytes + 255) & ~(size_t)255;
        return p;
    };
    int*            deg     = (int*)alloc((size_t)n * 4);
    size_t          zero_bytes = off;     // deg zeroed
    int*            offsets = (int*)alloc((size_t)n * 4);
    float*          dinv    = (float*)alloc((size_t)n * 4);
    int*            blkSums = (int*)alloc(64 * 4);
    short*          Bsw     = (short*)alloc((size_t)3 * 32768 * 2);
    unsigned short* rank    = (unsigned short*)alloc((size_t)e * 2);
    unsigned short* csr_src = (unsigned short*)alloc((size_t)e * 2);
    unsigned char*  xpack   = (unsigned char*)alloc((size_t)8 * n * 64);    // fp24 packed [8][n][64B]
    float*          buf1    = (float*)alloc((size_t)n * D * 4);             // fp32 h

    int eb256 = (e + 255) / 256;                           // 3125
    int scan_blocks = (n + SCAN_ELEMS - 1) / SCAN_ELEMS;   // 13 (<=64)
    int gemm_blocks = (n + 63) / 64;                       // 782
    int agg_grid = ((n + 31) / 32) * 8;                    // 12504

    hipMemsetAsync(ws, 0, zero_bytes, stream);
    count_wsplit_kernel<<<eb256 + 192, 256, 0, stream>>>(dst, deg, rank, e, eb256,
                                                         W1, W2, W3, Bsw);
    scanA_kernel<<<scan_blocks, 256, 0, stream>>>(deg, blkSums, n);
    scanC_kernel<<<scan_blocks, 256, 0, stream>>>(deg, blkSums, offsets, dinv, n, scan_blocks,
                                                  outp, bfc);
    fill_gemm_kernel<<<eb256 + gemm_blocks, 256, 0, stream>>>(src, dst, offsets, rank, csr_src,
                                                              e, eb256, x, Bsw, dinv,
                                                              xpack, n);
    aggc_kernel<false><<<agg_grid, 256, 0, stream>>>(xpack, csr_src, offsets, deg, dinv, b1,
                                                     buf1, nullptr, nullptr, n);
    gemm_kernel<<<gemm_blocks, 256, 0, stream>>>(buf1, Bsw + 32768, dinv, xpack, n);
    aggc_kernel<false><<<agg_grid, 256, 0, stream>>>(xpack, csr_src, offsets, deg, dinv, b2,
                                                     buf1, nullptr, nullptr, n);
    gemm_kernel<<<gemm_blocks, 256, 0, stream>>>(buf1, Bsw + 65536, dinv, xpack, n);
    aggc_kernel<true><<<agg_grid, 256, 0, stream>>>(xpack, csr_src, offsets, deg, dinv, b3,
                                                    nullptr, Wfc, outp, n);
}

// Round 3
// 322.457 us; speedup vs baseline: 1.8293x; 1.8293x over previous
//
#include <hip/hip_runtime.h>

#define D 128
#define SCAN_ELEMS 4096   // elements per scan block (256 threads x 16)

typedef __attribute__((ext_vector_type(8))) short short8;
typedef __attribute__((ext_vector_type(4))) float f32x4;

// ---------------- split-bf16 / fp24 helpers ----------------
__device__ inline void f2bf(float f, short& hi, short& lo) {
    union { float f; unsigned u; } a; a.f = f;
    unsigned r = a.u + 0x7fffu + ((a.u >> 16) & 1u);       // RNE to bf16
    hi = (short)(r >> 16);
    union { unsigned u; float f; } h; h.u = ((unsigned)(unsigned short)hi) << 16;
    union { float f; unsigned u; } b; b.f = f - h.f;
    unsigned r2 = b.u + 0x7fffu + ((b.u >> 16) & 1u);
    lo = (short)(r2 >> 16);
}

// fp24 encode: RNE-round fp32 to 24 bits (sign+8exp+15mant)
__device__ inline unsigned enc24(float f) {
    union { float f; unsigned u; } a; a.f = f;
    unsigned r = a.u + 0x7fu + ((a.u >> 8) & 1u);
    return r >> 8;
}

// ---------------- precompute: count (+fused wsplit) ----------------
// deg[] counts REAL edges only (self-loop handled as +1 at use sites).

__device__ void wsplit_body(int tid, const float* __restrict__ W1,
                            const float* __restrict__ W2, const float* __restrict__ W3,
                            short* __restrict__ Bsw) {
    int layer = tid >> 14;
    int rem = tid & 16383;
    int k = rem >> 7, c = rem & 127;
    const float* Wg = (layer == 0) ? W1 : ((layer == 1) ? W2 : W3);
    float v = Wg[k * 128 + c];
    short hi, lo; f2bf(v, hi, lo);
    int ktile = k >> 5, kk = k & 31, q = kk >> 3, j = kk & 7;
    int ct = c >> 4, mm = c & 15, lane = q * 16 + mm;
    int idx = layer * 32768 + ((ktile * 8 + ct) * 64 + lane) * 8 + j;
    Bsw[idx] = hi;
    Bsw[idx + 16384] = lo;
}

__global__ __launch_bounds__(256) void count_wsplit_kernel(const int* __restrict__ dst,
                                                           int* __restrict__ deg,
                                                           unsigned short* __restrict__ rank,
                                                           int e, int nbCount,
                                                           const float* __restrict__ W1,
                                                           const float* __restrict__ W2,
                                                           const float* __restrict__ W3,
                                                           short* __restrict__ Bsw) {
    if ((int)blockIdx.x < nbCount) {
        int i = blockIdx.x * 256 + threadIdx.x;
        if (i < e) rank[i] = (unsigned short)atomicAdd(&deg[dst[i]], 1);
    } else {
        int tid = (blockIdx.x - nbCount) * 256 + threadIdx.x;
        wsplit_body(tid, W1, W2, W3, Bsw);
    }
}

// ---- hierarchical scan ----
__global__ __launch_bounds__(256) void scanA_kernel(const int* __restrict__ deg,
                                                    int* __restrict__ blkSums, int n) {
    __shared__ int waveSums[4];
    int t = threadIdx.x;
    int base = blockIdx.x * SCAN_ELEMS + t * 16;
    int s = 0;
    if (base + 16 <= n) {
        const int4* p = reinterpret_cast<const int4*>(deg + base);
        #pragma unroll
        for (int k = 0; k < 4; ++k) {
            int4 v = p[k];
            s += v.x + v.y + v.z + v.w;
        }
    } else {
        for (int k = 0; k < 16; ++k) {
            int i = base + k;
            if (i < n) s += deg[i];
        }
    }
    #pragma unroll
    for (int off = 32; off > 0; off >>= 1) s += __shfl_down(s, off);
    int lane = t & 63, w = t >> 6;
    if (lane == 0) waveSums[w] = s;
    __syncthreads();
    if (t == 0) blkSums[blockIdx.x] = waveSums[0] + waveSums[1] + waveSums[2] + waveSums[3];
}

__global__ __launch_bounds__(256) void scanC_kernel(const int* __restrict__ deg,
                                                    const int* __restrict__ blkSums,
                                                    int* __restrict__ offsets,
                                                    float* __restrict__ dinv, int n, int nblk) {
    __shared__ int waveSums[4];
    __shared__ int blkBase;
    int t = threadIdx.x;
    int lane = t & 63, w = t >> 6;

    if (t < 64) {
        int s = (t < nblk && t < (int)blockIdx.x) ? blkSums[t] : 0;
        #pragma unroll
        for (int off = 32; off > 0; off >>= 1) s += __shfl_down(s, off);
        if (t == 0) blkBase = s;
    }

    int base = blockIdx.x * SCAN_ELEMS + t * 16;
    int v[16];
    int s = 0;
    #pragma unroll
    for (int k = 0; k < 16; ++k) {
        int i = base + k;
        int d = (i < n) ? deg[i] : 0;
        v[k] = d;
        s += d;
    }
    int incl = s;
    #pragma unroll
    for (int off = 1; off < 64; off <<= 1) {
        int u = __shfl_up(incl, off);
        if (lane >= off) incl += u;
    }
    if (lane == 63) waveSums[w] = incl;
    __syncthreads();
    int waveOff = 0;
    for (int i = 0; i < 4; ++i) if (i < w) waveOff += waveSums[i];
    int off0 = blkBase + waveOff + incl - s;

    #pragma unroll
    for (int k = 0; k < 16; ++k) {
        int i = base + k;
        if (i < n) {
            offsets[i] = off0;
            dinv[i] = rsqrtf((float)(v[k] + 1));   // +1 self-loop
            off0 += v[k];
        }
    }
}

// ---------------- split-bf16 MFMA GEMM body (no LDS, row-major fp24 dual out) ----------------
// SPLIT=false: A is fp32 [n][128], converted on the fly.
// SPLIT=true : A is pre-split bf16 pair arrays Ah/Al [n][128] (exact same math).
template<bool SPLIT>
__device__ void gemm_body(int blk, const float* __restrict__ A,
                          const unsigned short* __restrict__ Ah,
                          const unsigned short* __restrict__ Al,
                          const short* __restrict__ Bsw,
                          const float* __restrict__ dinv,
                          unsigned short* __restrict__ xh,
                          unsigned char* __restrict__ xl, int n, int t) {
    int w = t >> 6;
    int lane = t & 63;
    int quad = lane >> 4;
    int m = lane & 15;

    int rowBase = blk * 64 + w * 16;
    int arow = rowBase + m;
    bool valid = arow < n;
    int srow = valid ? arow : 0;

    f32x4 acc[8];
    #pragma unroll
    for (int ct = 0; ct < 8; ++ct) acc[ct] = (f32x4){0.f, 0.f, 0.f, 0.f};

    #pragma unroll
    for (int kt = 0; kt < 4; ++kt) {
        short8 a_hi, a_lo;
        if (SPLIT) {
            size_t off = (size_t)srow * D + kt * 32 + quad * 8;
            a_hi = *reinterpret_cast<const short8*>(Ah + off);
            a_lo = *reinterpret_cast<const short8*>(Al + off);
            // invalid rows feed garbage only into output rows >= n (never stored)
        } else {
            const float* ap = A + (size_t)srow * D + quad * 8;
            float4 f0 = *reinterpret_cast<const float4*>(ap + kt * 32);
            float4 f1 = *reinterpret_cast<const float4*>(ap + kt * 32 + 4);
            float fv[8] = {f0.x, f0.y, f0.z, f0.w, f1.x, f1.y, f1.z, f1.w};
            #pragma unroll
            for (int j = 0; j < 8; ++j) {
                short h, l; f2bf(valid ? fv[j] : 0.f, h, l);
                a_hi[j] = h; a_lo[j] = l;
            }
        }
        const short* bp = Bsw + (kt * 512 + lane) * 8;
        #pragma unroll
        for (int ct = 0; ct < 8; ++ct) {
            short8 b_hi = *reinterpret_cast<const short8*>(bp + ct * 512);
            short8 b_lo = *reinterpret_cast<const short8*>(bp + 16384 + ct * 512);
            acc[ct] = __builtin_amdgcn_mfma_f32_16x16x32_bf16(a_hi, b_hi, acc[ct], 0, 0, 0);
            acc[ct] = __builtin_amdgcn_mfma_f32_16x16x32_bf16(a_hi, b_lo, acc[ct], 0, 0, 0);
            acc[ct] = __builtin_amdgcn_mfma_f32_16x16x32_bf16(a_lo, b_hi, acc[ct], 0, 0, 0);
        }
    }

    // epilogue: C/D layout col=lane&15, row=quad*4+reg; row-major dual store
    #pragma unroll
    for (int r = 0; r < 4; ++r) {
        int row = rowBase + quad * 4 + r;
        if (row < n) {
            float s = dinv[row];
            size_t rb = (size_t)row * 128 + m;
            #pragma unroll
            for (int ct = 0; ct < 8; ++ct) {
                unsigned e24 = enc24(acc[ct][r] * s);
                xh[rb + ct * 16] = (unsigned short)(e24 >> 8);
                xl[rb + ct * 16] = (unsigned char)(e24 & 0xffu);
            }
        }
    }
}

__global__ __launch_bounds__(256) void gemm_split_kernel(const unsigned short* __restrict__ Ah,
                                                         const unsigned short* __restrict__ Al,
                                                         const short* __restrict__ Bsw,
                                                         const float* __restrict__ dinv,
                                                         unsigned short* __restrict__ xh,
                                                         unsigned char* __restrict__ xl, int n) {
    gemm_body<true>(blockIdx.x, nullptr, Ah, Al, Bsw, dinv, xh, xl, n, threadIdx.x);
}

// fill fused with layer-1 gemm (independent work, one dispatch)
__global__ __launch_bounds__(256) void fill_gemm_kernel(const int* __restrict__ src,
                                                        const int* __restrict__ dst,
                                                        const int* __restrict__ offsets,
                                                        const unsigned short* __restrict__ rank,
                                                        unsigned short* __restrict__ csr_src,
                                                        int e, int nbFill,
                                                        const float* __restrict__ A,
                                                        const short* __restrict__ Bsw,
                                                        const float* __restrict__ dinv,
                                                        unsigned short* __restrict__ xh,
                                                        unsigned char* __restrict__ xl, int n) {
    if ((int)blockIdx.x < nbFill) {
        int i = blockIdx.x * 256 + threadIdx.x;
        if (i < e) csr_src[offsets[dst[i]] + rank[i]] = (unsigned short)src[i];
    } else {
        gemm_body<false>(blockIdx.x - nbFill, A, nullptr, nullptr, Bsw, dinv, xh, xl, n, threadIdx.x);
    }
}

// ---------------- aggregation, quad-mapped (+ optional fused fc head) ----------------
// One wave per node. lane -> (q = edge-slot 0..3, s = col-group 0..15 covering 8 cols).
// Per edge gather: 16B hi (uint4) + 8B lo (uint2) per lane -> 8 fp24 decodes.
// Self-loop folded in as virtual edge (idx = node for lane >= cnt).
// Output h stored as split-bf16 pair (exactly what gemm's f2bf would compute).
template<bool FC>
__global__ __launch_bounds__(256) void aggq_kernel(const unsigned short* __restrict__ xh,
                                                   const unsigned char* __restrict__ xl,
                                                   const unsigned short* __restrict__ csr,
                                                   const int* __restrict__ offsets,
                                                   const int* __restrict__ deg,
                                                   const float* __restrict__ dinv,
                                                   const float* __restrict__ bias,
                                                   unsigned short* __restrict__ hh,
                                                   unsigned short* __restrict__ hl,
                                                   const float* __restrict__ fcw,
                                                   const float* __restrict__ fcb,
                                                   float* __restrict__ fcout,
                                                   int n) {
    int wave = (blockIdx.x * blockDim.x + threadIdx.x) >> 6;
    if (wave >= n) return;
    int lane = threadIdx.x & 63;
    int q = lane >> 4;        // edge slot
    int s = lane & 15;        // col group (8 cols)
    int node = wave;

    int base = offsets[node];
    int cnt  = deg[node];

    float4 aA0 = make_float4(0.f, 0.f, 0.f, 0.f), aA1 = make_float4(0.f, 0.f, 0.f, 0.f);
    float4 aB0 = make_float4(0.f, 0.f, 0.f, 0.f), aB1 = make_float4(0.f, 0.f, 0.f, 0.f);

    auto gq = [&](int row, float4& x0, float4& x1) {
        const unsigned short* hp = xh + ((size_t)row << 7) + s * 8;
        const unsigned char*  lp = xl + ((size_t)row << 7) + s * 8;
        uint4 h4 = *reinterpret_cast<const uint4*>(hp);
        uint2 l2 = *reinterpret_cast<const uint2*>(lp);
        union { unsigned u; float f; } e0, e1, e2, e3, e4, e5, e6, e7;
        e0.u = __builtin_amdgcn_perm(h4.x, l2.x, 0x0504000Cu);
        e1.u = __builtin_amdgcn_perm(h4.x, l2.x, 0x0706010Cu);
        e2.u = __builtin_amdgcn_perm(h4.y, l2.x, 0x0504020Cu);
        e3.u = __builtin_amdgcn_perm(h4.y, l2.x, 0x0706030Cu);
        e4.u = __builtin_amdgcn_perm(h4.z, l2.y, 0x0504000Cu);
        e5.u = __builtin_amdgcn_perm(h4.z, l2.y, 0x0706010Cu);
        e6.u = __builtin_amdgcn_perm(h4.w, l2.y, 0x0504020Cu);
        e7.u = __builtin_amdgcn_perm(h4.w, l2.y, 0x0706030Cu);
        x0.x += e0.f; x0.y += e1.f; x0.z += e2.f; x0.w += e3.f;
        x1.x += e4.f; x1.y += e5.f; x1.z += e6.f; x1.w += e7.f;
    };

    int total = cnt + 1;      // + virtual self-loop edge
    if (total <= 64) {
        int idx = (lane < cnt) ? (int)csr[base + lane] : node;
        for (int j = 0; j < total; j += 8) {
            int p0 = j + q, p1 = j + 4 + q;
            int s0 = __shfl(idx, p0 & 63);
            int s1 = __shfl(idx, p1 & 63);
            if (p0 < total) gq(s0, aA0, aA1);
            if (p1 < total) gq(s1, aB0, aB1);
        }
    } else {
        for (int j = 0; j < cnt; j += 8) {
            int p0 = j + q, p1 = j + 4 + q;
            if (p0 < cnt) gq((int)csr[base + p0], aA0, aA1);
            if (p1 < cnt) gq((int)csr[base + p1], aB0, aB1);
        }
        if (q == 0) gq(node, aA0, aA1);
    }

    aA0.x += aB0.x; aA0.y += aB0.y; aA0.z += aB0.z; aA0.w += aB0.w;
    aA1.x += aB1.x; aA1.y += aB1.y; aA1.z += aB1.z; aA1.w += aB1.w;
    #pragma unroll
    for (int off = 16; off < 64; off <<= 1) {
        aA0.x += __shfl_xor(aA0.x, off);
        aA0.y += __shfl_xor(aA0.y, off);
        aA0.z += __shfl_xor(aA0.z, off);
        aA0.w += __shfl_xor(aA0.w, off);
        aA1.x += __shfl_xor(aA1.x, off);
        aA1.y += __shfl_xor(aA1.y, off);
        aA1.z += __shfl_xor(aA1.z, off);
        aA1.w += __shfl_xor(aA1.w, off);
    }

    float di = dinv[node];
    float4 b0 = *reinterpret_cast<const float4*>(bias + s * 8);
    float4 b1 = *reinterpret_cast<const float4*>(bias + s * 8 + 4);
    float r0 = fmaxf(di * aA0.x + b0.x, 0.f);
    float r1 = fmaxf(di * aA0.y + b0.y, 0.f);
    float r2 = fmaxf(di * aA0.z + b0.z, 0.f);
    float r3 = fmaxf(di * aA0.w + b0.w, 0.f);
    float r4 = fmaxf(di * aA1.x + b1.x, 0.f);
    float r5 = fmaxf(di * aA1.y + b1.y, 0.f);
    float r6 = fmaxf(di * aA1.z + b1.z, 0.f);
    float r7 = fmaxf(di * aA1.w + b1.w, 0.f);

    if (FC) {
        float4 w0 = *reinterpret_cast<const float4*>(fcw + s * 8);
        float4 w1 = *reinterpret_cast<const float4*>(fcw + s * 8 + 4);
        float p = r0 * w0.x + r1 * w0.y + r2 * w0.z + r3 * w0.w
                + r4 * w1.x + r5 * w1.y + r6 * w1.z + r7 * w1.w;
        p += __shfl_xor(p, 1);
        p += __shfl_xor(p, 2);
        p += __shfl_xor(p, 4);
        p += __shfl_xor(p, 8);
        if (lane == 0) fcout[node] = p + fcb[0];
    } else if (q == 0) {
        short8 sh, sl;
        float rv[8] = {r0, r1, r2, r3, r4, r5, r6, r7};
        #pragma unroll
        for (int i = 0; i < 8; ++i) {
            short h, l; f2bf(rv[i], h, l);
            sh[i] = h; sl[i] = l;
        }
        size_t off = (size_t)node * D + s * 8;
        *reinterpret_cast<short8*>(hh + off) = sh;
        *reinterpret_cast<short8*>(hl + off) = sl;
    }
}

// ---------------- launch ----------------

extern "C" void kernel_launch(void* const* d_in, const int* in_sizes, int n_in,
                              void* d_out, int out_size, void* d_ws, size_t ws_size,
                              hipStream_t stream) {
    const float* x   = (const float*)d_in[0];
    const int*   ei  = (const int*)d_in[1];
    const float* W1  = (const float*)d_in[2];
    const float* b1  = (const float*)d_in[3];
    const float* W2  = (const float*)d_in[4];
    const float* b2  = (const float*)d_in[5];
    const float* W3  = (const float*)d_in[6];
    const float* b3  = (const float*)d_in[7];
    const float* Wfc = (const float*)d_in[8];
    const float* bfc = (const float*)d_in[9];
    float* outp = (float*)d_out;

    const int n = in_sizes[0] / D;        // 50000
    const int e = in_sizes[1] / 2;        // 800000
    const int* src = ei;
    const int* dst = ei + e;

    char* ws = (char*)d_ws;
    size_t off = 0;
    auto alloc = [&](size_t bytes) {
        void* p = ws + off;
        off += (bytes + 255) & ~(size_t)255;
        return p;
    };
    int*            deg     = (int*)alloc((size_t)n * 4);
    size_t          zero_bytes = off;     // deg zeroed
    int*            offsets = (int*)alloc((size_t)n * 4);
    float*          dinv    = (float*)alloc((size_t)n * 4);
    int*            blkSums = (int*)alloc(64 * 4);
    short*          Bsw     = (short*)alloc((size_t)3 * 32768 * 2);
    unsigned short* rank    = (unsigned short*)alloc((size_t)e * 2);
    unsigned short* csr_src = (unsigned short*)alloc((size_t)e * 2);
    unsigned short* xhbuf   = (unsigned short*)alloc((size_t)n * 128 * 2);  // fp24 hi16 [n][128]
    unsigned char*  xlbuf   = (unsigned char*)alloc((size_t)n * 128);       // fp24 lo8  [n][128]
    unsigned short* hhbuf   = (unsigned short*)alloc((size_t)n * 128 * 2);  // h split hi [n][128]
    unsigned short* hlbuf   = (unsigned short*)alloc((size_t)n * 128 * 2);  // h split lo [n][128]

    int eb256 = (e + 255) / 256;                           // 3125
    int scan_blocks = (n + SCAN_ELEMS - 1) / SCAN_ELEMS;   // 13 (<=64)
    int gemm_blocks = (n + 63) / 64;                       // 782
    int agg_blocks  = (n + 3) / 4;                         // 12500

    hipMemsetAsync(ws, 0, zero_bytes, stream);
    count_wsplit_kernel<<<eb256 + 192, 256, 0, stream>>>(dst, deg, rank, e, eb256,
                                                         W1, W2, W3, Bsw);
    scanA_kernel<<<scan_blocks, 256, 0, stream>>>(deg, blkSums, n);
    scanC_kernel<<<scan_blocks, 256, 0, stream>>>(deg, blkSums, offsets, dinv, n, scan_blocks);
    fill_gemm_kernel<<<eb256 + gemm_blocks, 256, 0, stream>>>(src, dst, offsets, rank, csr_src,
                                                              e, eb256, x, Bsw, dinv,
                                                              xhbuf, xlbuf, n);
    aggq_kernel<false><<<agg_blocks, 256, 0, stream>>>(xhbuf, xlbuf, csr_src, offsets, deg, dinv,
                                                       b1, hhbuf, hlbuf, nullptr, nullptr, nullptr, n);
    gemm_split_kernel<<<gemm_blocks, 256, 0, stream>>>(hhbuf, hlbuf, Bsw + 32768, dinv,
                                                       xhbuf, xlbuf, n);
    aggq_kernel<false><<<agg_blocks, 256, 0, stream>>>(xhbuf, xlbuf, csr_src, offsets, deg, dinv,
                                                       b2, hhbuf, hlbuf, nullptr, nullptr, nullptr, n);
    gemm_split_kernel<<<gemm_blocks, 256, 0, stream>>>(hhbuf, hlbuf, Bsw + 65536, dinv,
                                                       xhbuf, xlbuf, n);
    aggq_kernel<true><<<agg_blocks, 256, 0, stream>>>(xhbuf, xlbuf, csr_src, offsets, deg, dinv,
                                                      b3, nullptr, nullptr, Wfc, bfc, outp, n);
}